// Round 9
// baseline (94.481 us; speedup 1.0000x reference)
//
#include <hip/hip_runtime.h>

#define BN 8192
#define DD 128
#define NC 64
#define ALPHA 2.0f
#define BETA 50.0f
#define BASE 0.5f
#define MARGIN 0.1f
#define ROWT 128
#define COLT 64
#define NSPLIT 32
#define CPS (BN / NSPLIT)                /* 256 */
#define NEGBLKS ((BN / ROWT) * NSPLIT)   /* 2048 */
#define CLSBLKS (NC * 2)                 /* 128 */
#define SCALE_D 4294967296.0             /* 2^32 fixed-point for deterministic atomics */

// exp/exp2 folding: exp(B*(s-BASE)) = exp2(fma(s, B*log2e, -B*BASE*log2e))
#define NEG_K1 72.13475204444817f
#define NEG_K0 -36.067376022224085f
#define POS_K1 -2.8853900817779268f
#define POS_K0 1.4426950408889634f

typedef __attribute__((ext_vector_type(8))) short short8v;
typedef __attribute__((ext_vector_type(4))) float f32x4;
typedef __attribute__((ext_vector_type(4))) int int4v;

__device__ __forceinline__ float exp2_fast(float x) {
#if __has_builtin(__builtin_amdgcn_exp2f)
    return __builtin_amdgcn_exp2f(x);
#else
    return __expf(x * 0.6931471805599453f);
#endif
}

__device__ __forceinline__ unsigned short f2bf(float x) {
    union { float f; unsigned u; } q; q.f = x;
    unsigned r = q.u + 0x7fffu + ((q.u >> 16) & 1u);   // RNE
    return (unsigned short)(r >> 16);
}

// ---------------- K0: cvt (blocks 0..1023) + bucketing (1024..1087) + accum zeroing ----------------
__global__ __launch_bounds__(256) void k0_fused(const float* __restrict__ emb,
                                                const int* __restrict__ lab,
                                                unsigned short* __restrict__ ebf,
                                                int* __restrict__ offsets,
                                                int* __restrict__ memb,
                                                unsigned long long* __restrict__ accums) {
    const int b = blockIdx.x;
    const int t = threadIdx.x;
    if (b < BN * DD / 1024) {
        int idx = (b * 256 + t) * 4;
        float4 v = *(const float4*)(emb + idx);
        ushort4 o;
        o.x = f2bf(v.x); o.y = f2bf(v.y); o.z = f2bf(v.z); o.w = f2bf(v.w);
        *(ushort4*)(ebf + idx) = o;
        return;
    }
    const int c = b - BN * DD / 1024;
    if (c == 0 && t >= 64 && t < 67) accums[t - 64] = 0ull;   // loss, cnt, done
    if (t < 64) {
        int below = 0;
        for (int j = t; j < BN; j += 64) below += (lab[j] < c) ? 1 : 0;
#pragma unroll
        for (int d = 1; d < 64; d <<= 1) below += __shfl_xor(below, d);
        if (t == 0) {
            offsets[c] = below;
            if (c == 0) offsets[NC] = BN;
        }
        int cur = below;
        for (int j0 = 0; j0 < BN; j0 += 64) {
            const bool m = (lab[j0 + t] == c);
            unsigned long long bal = __ballot(m);
            int bel = __popcll(bal & ((1ULL << t) - 1ULL));
            if (m) memb[cur + bel] = j0 + t;
            cur += __popcll(bal);
        }
    }
}

// ---------------- K2b: neg pass (blocks 0..2047) + per-class pos_min (2048..2175) ----------------
__global__ __launch_bounds__(256) void k2b(const unsigned short* __restrict__ ebf,
                                           const int* __restrict__ lab,
                                           const int* __restrict__ offsets,
                                           const int* __restrict__ memb,
                                           float* __restrict__ nmax_part,
                                           float* __restrict__ nsum_part,
                                           float* __restrict__ pos_min) {
    __shared__ __align__(16) unsigned short Bs[COLT * DD];   // single buffer, 16 KB
    __shared__ int labs[COLT];

    const int t = threadIdx.x;
    const int w = t >> 6;
    const int l = t & 63;
    const int l15 = l & 15;
    const int lq = l >> 4;

    if (blockIdx.x >= NEGBLKS) {
        // ---- pos_min class blocks ----
        const int bid = blockIdx.x - NEGBLKS;
        const int c = bid & (NC - 1);
        const int rs = bid >> 6;
        const int off = offsets[c];
        const int M = offsets[c + 1] - off;
        if (M == 0) return;

        for (int r0 = rs * 64; r0 < M; r0 += 128) {
            const int slot_a = r0 + w * 16 + l15;
            const int arow = memb[off + (slot_a < M ? slot_a : M - 1)];
            short8v afrag[4];
#pragma unroll
            for (int ks = 0; ks < 4; ++ks)
                afrag[ks] = *(const short8v*)(ebf + (size_t)arow * DD + ks * 32 + lq * 8);

            int mr[4]; float pmin[4];
#pragma unroll
            for (int q = 0; q < 4; ++q) {
                int sq = r0 + w * 16 + lq * 4 + q;
                mr[q] = (sq < M) ? memb[off + sq] : -1;
                pmin[q] = __builtin_inff();
            }

            for (int c0 = 0; c0 < M; c0 += COLT) {
                __syncthreads();
                for (int u = t; u < 1024; u += 256) {
                    int cc = u >> 4, kb = u & 15;
                    int cs = c0 + cc;
                    int crow = memb[off + (cs < M ? cs : M - 1)];
                    int4v v = *(const int4v*)(ebf + (size_t)crow * DD + kb * 8);
                    int byte = (cc << 8) + (kb << 4);
                    byte ^= (cc & 7) << 4;
                    *(int4v*)((char*)Bs + byte) = v;
                }
                if (t < COLT) labs[t] = (c0 + t < M) ? memb[off + c0 + t] : -1;
                __syncthreads();

#pragma unroll
                for (int cf = 0; cf < 4; ++cf) {
                    const int cc = cf * 16 + l15;
                    short8v bfrag[4];
#pragma unroll
                    for (int ks = 0; ks < 4; ++ks) {
                        int byte = (cc << 8) + ks * 64 + lq * 16;
                        byte ^= (cc & 7) << 4;
                        bfrag[ks] = *(const short8v*)((const char*)Bs + byte);
                    }
                    f32x4 acc = { 0.f, 0.f, 0.f, 0.f };
#pragma unroll
                    for (int ks = 0; ks < 4; ++ks)
                        acc = __builtin_amdgcn_mfma_f32_16x16x32_bf16(afrag[ks], bfrag[ks], acc, 0, 0, 0);
                    const int mc = labs[cf * 16 + l15];
#pragma unroll
                    for (int q = 0; q < 4; ++q) {
                        float sv = (mc >= 0 && mc != mr[q]) ? acc[q] : __builtin_inff();
                        pmin[q] = fminf(pmin[q], sv);
                    }
                }
            }

#pragma unroll
            for (int q = 0; q < 4; ++q) {
                float m = pmin[q];
#pragma unroll
                for (int d = 1; d < 16; d <<= 1) m = fminf(m, __shfl_xor(m, d));
                if (l15 == 0 && mr[q] >= 0) pos_min[mr[q]] = m;
            }
        }
        return;
    }

    // ---- neg pass: full Gram, class-masked nsum/nmax, single-buffer 2-barrier pipeline ----
    const int rb = blockIdx.x / NSPLIT;
    const int split = blockIdx.x % NSPLIT;
    const int row0 = rb * ROWT;
    const int col0 = split * CPS;

    short8v afrag[2][4];
#pragma unroll
    for (int s = 0; s < 2; ++s) {
        const int arow = row0 + s * 64 + w * 16 + l15;
#pragma unroll
        for (int ks = 0; ks < 4; ++ks)
            afrag[s][ks] = *(const short8v*)(ebf + (size_t)arow * DD + ks * 32 + lq * 8);
    }

    int labr[2][4];
    float nmax[2][4], nsum[2][4];
#pragma unroll
    for (int s = 0; s < 2; ++s)
#pragma unroll
        for (int q = 0; q < 4; ++q) {
            int r = row0 + s * 64 + w * 16 + lq * 4 + q;
            labr[s][q] = lab[r];
            nmax[s][q] = -__builtin_inff();
            nsum[s][q] = 0.f;
        }

    const int NT = CPS / COLT;   // 4 tiles
    int4v stg[4]; int stglab;

    {   // prologue: load tile 0 to regs, write to LDS
        const int cbase = col0;
#pragma unroll
        for (int k = 0; k < 4; ++k) {
            int u = t + k * 256, cc = u >> 4, kb = u & 15;
            stg[k] = *(const int4v*)(ebf + (size_t)(cbase + cc) * DD + kb * 8);
        }
        stglab = lab[cbase + (t & (COLT - 1))];
#pragma unroll
        for (int k = 0; k < 4; ++k) {
            int u = t + k * 256, cc = u >> 4, kb = u & 15;
            int byte = (cc << 8) + (kb << 4);
            byte ^= (cc & 7) << 4;
            *(int4v*)((char*)Bs + byte) = stg[k];
        }
        if (t < COLT) labs[t] = stglab;
    }

    for (int tt = 0; tt < NT; ++tt) {
        __syncthreads();   // tile tt's LDS writes visible

        if (tt + 1 < NT) {   // issue next tile's global loads early
            const int cbase = col0 + (tt + 1) * COLT;
#pragma unroll
            for (int k = 0; k < 4; ++k) {
                int u = t + k * 256, cc = u >> 4, kb = u & 15;
                stg[k] = *(const int4v*)(ebf + (size_t)(cbase + cc) * DD + kb * 8);
            }
            stglab = lab[cbase + (t & (COLT - 1))];
        }

#pragma unroll
        for (int cf = 0; cf < 4; ++cf) {
            const int cc = cf * 16 + l15;
            short8v bfrag[4];
#pragma unroll
            for (int ks = 0; ks < 4; ++ks) {
                int byte = (cc << 8) + ks * 64 + lq * 16;
                byte ^= (cc & 7) << 4;
                bfrag[ks] = *(const short8v*)((const char*)Bs + byte);
            }
            f32x4 acc0 = { 0.f, 0.f, 0.f, 0.f };
            f32x4 acc1 = { 0.f, 0.f, 0.f, 0.f };
#pragma unroll
            for (int ks = 0; ks < 4; ++ks) {
                acc0 = __builtin_amdgcn_mfma_f32_16x16x32_bf16(afrag[0][ks], bfrag[ks], acc0, 0, 0, 0);
                acc1 = __builtin_amdgcn_mfma_f32_16x16x32_bf16(afrag[1][ks], bfrag[ks], acc1, 0, 0, 0);
            }

            const int labc = labs[cf * 16 + l15];
#pragma unroll
            for (int q = 0; q < 4; ++q) {
                float sv0 = (labc != labr[0][q]) ? acc0[q] : -__builtin_inff();
                nmax[0][q] = fmaxf(nmax[0][q], sv0);
                nsum[0][q] += exp2_fast(fmaf(sv0, NEG_K1, NEG_K0));
                float sv1 = (labc != labr[1][q]) ? acc1[q] : -__builtin_inff();
                nmax[1][q] = fmaxf(nmax[1][q], sv1);
                nsum[1][q] += exp2_fast(fmaf(sv1, NEG_K1, NEG_K0));
            }
        }

        __syncthreads();   // all reads of tile tt done

        if (tt + 1 < NT) {   // write next tile into LDS
#pragma unroll
            for (int k = 0; k < 4; ++k) {
                int u = t + k * 256, cc = u >> 4, kb = u & 15;
                int byte = (cc << 8) + (kb << 4);
                byte ^= (cc & 7) << 4;
                *(int4v*)((char*)Bs + byte) = stg[k];
            }
            if (t < COLT) labs[t] = stglab;
        }
    }

#pragma unroll
    for (int s = 0; s < 2; ++s)
#pragma unroll
    for (int q = 0; q < 4; ++q) {
        float m = nmax[s][q], sm = nsum[s][q];
#pragma unroll
        for (int d = 1; d < 16; d <<= 1) {
            m = fmaxf(m, __shfl_xor(m, d));
            sm += __shfl_xor(sm, d);
        }
        if (l15 == 0) {
            int r = row0 + s * 64 + w * 16 + lq * 4 + q;
            nmax_part[(size_t)r * NSPLIT + split] = m;
            nsum_part[(size_t)r * NSPLIT + split] = sm;
        }
    }
}

// ---------------- K3f: per-class pos_sum + loss + deterministic atomic finalize ----------------
__global__ __launch_bounds__(256) void k3_final(const unsigned short* __restrict__ ebf,
                                                const int* __restrict__ offsets,
                                                const int* __restrict__ memb,
                                                const float* __restrict__ nmax_part,
                                                const float* __restrict__ nsum_part,
                                                const float* __restrict__ pos_min,
                                                unsigned long long* __restrict__ accums,
                                                float* __restrict__ out) {
    __shared__ __align__(16) unsigned short Bs[COLT * DD];
    __shared__ int mcol[COLT];
    __shared__ float redl[256], redc[256];
    const int c = blockIdx.x & (NC - 1);
    const int rs = blockIdx.x >> 6;
    const int off = offsets[c];
    const int M = offsets[c + 1] - off;
    const int t = threadIdx.x, w = t >> 6, l = t & 63, l15 = l & 15, lq = l >> 4;

    float loss_acc = 0.f, cnt_acc = 0.f;

    if (M > 0)
    for (int r0 = rs * 64; r0 < M; r0 += 128) {
        const int slot_a = r0 + w * 16 + l15;
        const int arow = memb[off + (slot_a < M ? slot_a : M - 1)];
        short8v afrag[4];
#pragma unroll
        for (int ks = 0; ks < 4; ++ks)
            afrag[ks] = *(const short8v*)(ebf + (size_t)arow * DD + ks * 32 + lq * 8);

        int mr[4]; float pthr[4], nmv[4], nsv[4], pmv[4], psum[4];
#pragma unroll
        for (int q = 0; q < 4; ++q) {
            int sq = r0 + w * 16 + lq * 4 + q;
            mr[q] = (sq < M) ? memb[off + sq] : -1;
            psum[q] = 0.f;
            float nm = -__builtin_inff(), ns = 0.f;
            if (mr[q] >= 0) {
                for (int p = 0; p < NSPLIT; ++p) {
                    nm = fmaxf(nm, nmax_part[(size_t)mr[q] * NSPLIT + p]);
                    ns += nsum_part[(size_t)mr[q] * NSPLIT + p];
                }
            }
            nmv[q] = nm; nsv[q] = ns;
            pmv[q] = (mr[q] >= 0) ? pos_min[mr[q]] : 0.f;
            pthr[q] = nm + MARGIN;
        }

        for (int c0 = 0; c0 < M; c0 += COLT) {
            __syncthreads();
            for (int u = t; u < 1024; u += 256) {
                int cc = u >> 4, kb = u & 15;
                int cs = c0 + cc;
                int crow = memb[off + (cs < M ? cs : M - 1)];
                int4v v = *(const int4v*)(ebf + (size_t)crow * DD + kb * 8);
                int byte = (cc << 8) + (kb << 4);
                byte ^= (cc & 7) << 4;
                *(int4v*)((char*)Bs + byte) = v;
            }
            if (t < COLT) mcol[t] = (c0 + t < M) ? memb[off + c0 + t] : -1;
            __syncthreads();

#pragma unroll
            for (int cf = 0; cf < 4; ++cf) {
                const int cc = cf * 16 + l15;
                short8v bfrag[4];
#pragma unroll
                for (int ks = 0; ks < 4; ++ks) {
                    int byte = (cc << 8) + ks * 64 + lq * 16;
                    byte ^= (cc & 7) << 4;
                    bfrag[ks] = *(const short8v*)((const char*)Bs + byte);
                }
                f32x4 acc = { 0.f, 0.f, 0.f, 0.f };
#pragma unroll
                for (int ks = 0; ks < 4; ++ks)
                    acc = __builtin_amdgcn_mfma_f32_16x16x32_bf16(afrag[ks], bfrag[ks], acc, 0, 0, 0);
                const int mc = mcol[cf * 16 + l15];
#pragma unroll
                for (int q = 0; q < 4; ++q) {
                    float s = acc[q];
                    float sv = (mc >= 0 && mc != mr[q] && s < pthr[q]) ? s : __builtin_inff();
                    psum[q] += exp2_fast(fmaf(sv, POS_K1, POS_K0));
                }
            }
        }

#pragma unroll
        for (int q = 0; q < 4; ++q) {
            float ps = psum[q];
#pragma unroll
            for (int d = 1; d < 16; d <<= 1) ps += __shfl_xor(ps, d);
            if (l15 == 0 && mr[q] >= 0) {
                bool valid = (M >= 2) && (M < BN) && (nmv[q] > pmv[q] - MARGIN) && (ps > 0.f);
                float loss = log1pf(ps) / ALPHA + log1pf(nsv[q]) / BETA;
                loss_acc += valid ? loss : 0.f;
                cnt_acc  += valid ? 1.f : 0.f;
            }
        }
    }

    __syncthreads();
    redl[t] = loss_acc; redc[t] = cnt_acc;
    __syncthreads();
    for (int s = 128; s > 0; s >>= 1) {
        if (t < s) { redl[t] += redl[t + s]; redc[t] += redc[t + s]; }
        __syncthreads();
    }
    if (t == 0) {
        atomicAdd(&accums[0], (unsigned long long)((double)redl[0] * SCALE_D + 0.5));
        atomicAdd(&accums[1], (unsigned long long)(redc[0] + 0.5f));
        __threadfence();
        unsigned long long old = atomicAdd(&accums[2], 1ull);
        if (old == (unsigned long long)(CLSBLKS - 1)) {
            __threadfence();
            unsigned long long li = atomicAdd(&accums[0], 0ull);
            unsigned long long ci = atomicAdd(&accums[1], 0ull);
            double L = (double)li / SCALE_D;
            out[0] = (ci > 0ull) ? (float)(L / (double)ci) : 0.f;
        }
    }
}

extern "C" void kernel_launch(void* const* d_in, const int* in_sizes, int n_in,
                              void* d_out, int out_size, void* d_ws, size_t ws_size,
                              hipStream_t stream) {
    const float* emb = (const float*)d_in[0];
    const int* lab = (const int*)d_in[1];
    float* out = (float*)d_out;

    char* ws = (char*)d_ws;
    unsigned short* ebf = (unsigned short*)ws;                   // 2 MB
    float* pos_min   = (float*)(ws + (size_t)BN * DD * 2);
    float* nmax_part = pos_min + BN;
    float* nsum_part = nmax_part + (size_t)BN * NSPLIT;
    unsigned long long* accums = (unsigned long long*)(nsum_part + (size_t)BN * NSPLIT); // 3 ull
    int*   offsets   = (int*)(accums + 4);                       // NC+1
    int*   memb      = offsets + (NC + 1);                       // BN

    k0_fused<<<BN * DD / 1024 + NC, 256, 0, stream>>>(emb, lab, ebf, offsets, memb, accums);
    k2b<<<NEGBLKS + CLSBLKS, 256, 0, stream>>>(ebf, lab, offsets, memb, nmax_part, nsum_part, pos_min);
    k3_final<<<CLSBLKS, 256, 0, stream>>>(ebf, offsets, memb, nmax_part, nsum_part, pos_min, accums, out);
}